// Round 9
// baseline (525.382 us; speedup 1.0000x reference)
//
#include <hip/hip_runtime.h>
#include <math.h>

#define NN 8192
#define FF 256
#define ALPHA 0.2f
#define SS 8                 // j-segments
#define JSEG (NN / SS)       // 1024
#define STEPS (JSEG / 32)    // 32 (32-j words); 64 half-steps of 16 j
#define BI 128               // i-rows per k3 block (4 waves x 32 rows)

typedef __bf16 bf16x8 __attribute__((ext_vector_type(8)));
typedef __bf16 bf16x4 __attribute__((ext_vector_type(4)));
typedef float  f32x4  __attribute__((ext_vector_type(4)));
typedef float  f32x16 __attribute__((ext_vector_type(16)));

// ---------------- K0: WT[hl][n][k] bf16 hi/lo from W[k][n] fp32 -----------
__global__ __launch_bounds__(256) void k0_wt(const float* __restrict__ W,
                                             __bf16* __restrict__ WT) {
    __shared__ float ts[64][65];
    const int t = threadIdx.x;
    const int k0 = blockIdx.x * 64;
    const int n0 = blockIdx.y * 64;
    #pragma unroll
    for (int r = 0; r < 4; ++r) {
        int krow = r * 16 + (t >> 4);
        int nc4 = (t & 15) * 4;
        *(float4*)&ts[krow][nc4] = *(const float4*)&W[(size_t)(k0 + krow) * FF + n0 + nc4];
    }
    __syncthreads();
    const int nloc = t >> 2;
    const int kc = (t & 3) * 16;
    union { bf16x8 v[2]; __bf16 e[16]; } hi, lo;
    #pragma unroll
    for (int u = 0; u < 16; ++u) {
        float x = ts[kc + u][nloc];
        __bf16 h1 = (__bf16)x;
        hi.e[u] = h1;
        lo.e[u] = (__bf16)(x - (float)h1);
    }
    size_t base = (size_t)(n0 + nloc) * FF + k0 + kc;
    *(bf16x8*)&WT[base] = hi.v[0];
    *(bf16x8*)&WT[base + 8] = hi.v[1];
    size_t lbase = (size_t)FF * FF + base;
    *(bf16x8*)&WT[lbase] = lo.v[0];
    *(bf16x8*)&WT[lbase + 8] = lo.v[1];
}

// ---------------- K1: MFMA h-tile -> hT(hi, transposed) + src/dst ---------
__global__ __launch_bounds__(256) void k1_h(const float* __restrict__ X,
                                            const __bf16* __restrict__ WT,
                                            const float* __restrict__ a,
                                            __bf16* __restrict__ hT,
                                            float* __restrict__ src,
                                            float* __restrict__ dst) {
    __shared__ __bf16 ax[2][32][40];
    __shared__ float hs[32][264];
    __shared__ float red[2][4][32];
    const int t = threadIdx.x;
    const int i0 = blockIdx.x * 32;
    const int l = t & 63, wv = t >> 6, ln = l & 15, g = l >> 4;
    f32x4 acc[2][4];
    #pragma unroll
    for (int mt = 0; mt < 2; ++mt)
        #pragma unroll
        for (int nt = 0; nt < 4; ++nt)
            acc[mt][nt] = (f32x4){0.f, 0.f, 0.f, 0.f};

    for (int ks = 0; ks < 8; ++ks) {
        const int k0 = ks * 32;
        {
            int row = t >> 3, c4 = (t & 7) * 4;
            float4 xv = *(const float4*)&X[(size_t)(i0 + row) * FF + k0 + c4];
            bf16x4 hi4, lo4;
            float xs_[4] = {xv.x, xv.y, xv.z, xv.w};
            #pragma unroll
            for (int u = 0; u < 4; ++u) {
                __bf16 h1 = (__bf16)xs_[u];
                hi4[u] = h1;
                lo4[u] = (__bf16)(xs_[u] - (float)h1);
            }
            *(bf16x4*)&ax[0][row][c4] = hi4;
            *(bf16x4*)&ax[1][row][c4] = lo4;
        }
        __syncthreads();
        bf16x8 ah[2], al[2];
        ah[0] = *(bf16x8*)&ax[0][ln][g * 8];
        ah[1] = *(bf16x8*)&ax[0][16 + ln][g * 8];
        al[0] = *(bf16x8*)&ax[1][ln][g * 8];
        al[1] = *(bf16x8*)&ax[1][16 + ln][g * 8];
        #pragma unroll
        for (int nt = 0; nt < 4; ++nt) {
            const int n = wv * 64 + nt * 16 + ln;
            bf16x8 bh8 = *(const bf16x8*)&WT[(size_t)n * FF + k0 + g * 8];
            bf16x8 bl8 = *(const bf16x8*)&WT[(size_t)(FF + n) * FF + k0 + g * 8];
            #pragma unroll
            for (int mt = 0; mt < 2; ++mt) {
                acc[mt][nt] = __builtin_amdgcn_mfma_f32_16x16x32_bf16(ah[mt], bh8, acc[mt][nt], 0, 0, 0);
                acc[mt][nt] = __builtin_amdgcn_mfma_f32_16x16x32_bf16(ah[mt], bl8, acc[mt][nt], 0, 0, 0);
                acc[mt][nt] = __builtin_amdgcn_mfma_f32_16x16x32_bf16(al[mt], bh8, acc[mt][nt], 0, 0, 0);
            }
        }
        __syncthreads();
    }
    float an[4], ad[4];
    #pragma unroll
    for (int nt = 0; nt < 4; ++nt) {
        an[nt] = a[wv * 64 + nt * 16 + ln];
        ad[nt] = a[FF + wv * 64 + nt * 16 + ln];
    }
    float sp[2][4], dp[2][4];
    #pragma unroll
    for (int mt = 0; mt < 2; ++mt)
        #pragma unroll
        for (int rg = 0; rg < 4; ++rg) { sp[mt][rg] = 0.f; dp[mt][rg] = 0.f; }
    #pragma unroll
    for (int mt = 0; mt < 2; ++mt)
        #pragma unroll
        for (int nt = 0; nt < 4; ++nt)
            #pragma unroll
            for (int rg = 0; rg < 4; ++rg) {
                float v = acc[mt][nt][rg];
                hs[mt * 16 + g * 4 + rg][wv * 64 + nt * 16 + ln] = v;
                sp[mt][rg] += v * an[nt];
                dp[mt][rg] += v * ad[nt];
            }
    #pragma unroll
    for (int mk = 1; mk < 16; mk <<= 1)
        #pragma unroll
        for (int mt = 0; mt < 2; ++mt)
            #pragma unroll
            for (int rg = 0; rg < 4; ++rg) {
                sp[mt][rg] += __shfl_xor(sp[mt][rg], mk);
                dp[mt][rg] += __shfl_xor(dp[mt][rg], mk);
            }
    if (ln == 0) {
        #pragma unroll
        for (int mt = 0; mt < 2; ++mt)
            #pragma unroll
            for (int rg = 0; rg < 4; ++rg) {
                red[0][wv][mt * 16 + g * 4 + rg] = sp[mt][rg];
                red[1][wv][mt * 16 + g * 4 + rg] = dp[mt][rg];
            }
    }
    __syncthreads();
    if (t < 32) {
        src[i0 + t] = red[0][0][t] + red[0][1][t] + red[0][2][t] + red[0][3][t];
        dst[i0 + t] = red[1][0][t] + red[1][1][t] + red[1][2][t] + red[1][3][t];
    }
    {
        const int f = t;
        #pragma unroll
        for (int jc = 0; jc < 4; ++jc) {
            union { bf16x8 v; __bf16 e[8]; } hi;
            #pragma unroll
            for (int u = 0; u < 8; ++u) {
                float x = hs[jc * 8 + u][f];
                hi.e[u] = (__bf16)x;
            }
            *(bf16x8*)&hT[(size_t)f * NN + i0 + jc * 8] = hi.v;
        }
    }
}

// ---------------- K2a: pack adj int32 -> 1 bit/elem (natural j order) -----
__global__ __launch_bounds__(256) void k2a_pack(const int* __restrict__ adj,
                                                unsigned* __restrict__ bits) {
    const size_t total4 = (size_t)NN * NN / 4;
    const int l = threadIdx.x & 63;
    const int base = l & 56;
    size_t t = (size_t)blockIdx.x * 256 + threadIdx.x;
    const size_t stride = (size_t)gridDim.x * 256;
    for (; t < total4; t += stride) {
        int4 v = ((const int4*)adj)[t];
        unsigned nib = (unsigned)(v.x > 0) | ((unsigned)(v.y > 0) << 1)
                     | ((unsigned)(v.z > 0) << 2) | ((unsigned)(v.w > 0) << 3);
        unsigned w = 0;
        #pragma unroll
        for (int k = 0; k < 8; ++k)
            w |= (unsigned)__shfl((int)nib, base + k) << (4 * k);
        if ((l & 7) == 0)
            bits[t >> 3] = w;
    }
}

// ---------------- K2b: maxd = max_j dst_j ---------------------------------
__global__ __launch_bounds__(256) void k2b_max(const float* __restrict__ dst,
                                               float* __restrict__ maxd) {
    __shared__ float red[256];
    float m = -1e30f;
    #pragma unroll
    for (int r = 0; r < NN / 1024; ++r) {
        float4 v = *(const float4*)&dst[(r * 256 + threadIdx.x) * 4];
        m = fmaxf(m, fmaxf(fmaxf(v.x, v.y), fmaxf(v.z, v.w)));
    }
    red[threadIdx.x] = m;
    __syncthreads();
    for (int s = 128; s > 0; s >>= 1) {
        if (threadIdx.x < s) red[threadIdx.x] = fmaxf(red[threadIdx.x], red[threadIdx.x + s]);
        __syncthreads();
    }
    if (threadIdx.x == 0) maxd[0] = red[0];
}

// ---------------- K3: wave-autonomous, barrier-free MFMA attention --------
// R0-R7 post-mortem: six schedule/volume levers inside the barrier-lockstep
// template were all null (k3 pinned ~100-180us). This removes the template:
// no in-loop barriers, no LDS B-tile, no DMA. Each wave owns 32 rows
// (R7-verified 32x32x16 layouts) and streams B-fragments DIRECTLY from
// L2-resident hT (4 MB; seg->XCD affinity via seg = bid&7 keeps each seg's
// 512 KB slice in one XCD's L2). Half-step = 16 j: prefetch next 8 B-frags
// (ping-pong regs, static indices), WCOMP one A-frag (8 exp), 8 MFMAs.
// Compiler software-pipelines freely (counted vmcnt, nothing to drain).
// LDS: only the 4 KB dst segment (one prologue barrier).
__global__ __launch_bounds__(256, 2) void k3_attn(const unsigned* __restrict__ bits,
                                                  const __bf16* __restrict__ hT,
                                                  const float* __restrict__ src,
                                                  const float* __restrict__ dst,
                                                  const float* __restrict__ maxd,
                                                  float* __restrict__ num,
                                                  float* __restrict__ den) {
    __shared__ float dsts[JSEG];            // 4 KB dst segment
    const int t = threadIdx.x;
    const int l = t & 63, wv = t >> 6;      // 4 waves
    const int q = l & 31, hi = l >> 5;      // row-in-wave-tile, k-half
    const int seg = blockIdx.x & 7;         // seg -> XCD affinity (bid % 8)
    const int it = blockIdx.x >> 3;         // 64 i-tiles
    const int i0 = it * BI;
    const int jbeg = seg * JSEG;
    const int row = i0 + wv * 32 + q;
    const float maxdv = maxd[0];
    const float src_r = src[row];
    const float e0 = src_r + maxdv;
    const float m_r = e0 > 0.f ? e0 : ALPHA * e0;   // per-row shift >= row max

    // stage dst segment (only LDS use; single prologue barrier)
    *(float4*)&dsts[t * 4] = *(const float4*)&dst[jbeg + t * 4];
    __syncthreads();

    // B source base: col f = ft*32+q, k elems at j16 + 8*hi (16B aligned)
    const __bf16* bp = hT + (size_t)q * NN + 8 * hi;
    // mask source: word s covers j = jbeg + s*32 + b
    const unsigned* grow = bits + (size_t)row * (NN / 32) + (jbeg >> 5);

    float den_reg = 0.f;
    f32x16 acc[8];
    #pragma unroll
    for (int ft = 0; ft < 8; ++ft)
        #pragma unroll
        for (int rg = 0; rg < 16; ++rg) acc[ft][rg] = 0.f;

#define K3_LOADB(B_, J16_)                                                    \
    {                                                                         \
        _Pragma("unroll")                                                     \
        for (int ft = 0; ft < 8; ++ft)                                        \
            B_[ft] = *(const bf16x8*)(bp + (size_t)ft * 32 * NN + (J16_));    \
    }

    // WCOMP half-step: lane covers row q, j = jbeg + s*32 + koff + 8*hi + u
#define K3_WCOMP(S_, MW_, KOFF_, AF_)                                         \
    {                                                                         \
        unsigned mb = ((MW_) >> ((KOFF_) + 8 * hi)) & 0xffu;                  \
        const float* dp_ = &dsts[(S_) * 32 + (KOFF_) + 8 * hi];               \
        float4 dq0 = *(const float4*)dp_;                                     \
        float4 dq1 = *(const float4*)(dp_ + 4);                               \
        const float dv[8] = {dq0.x, dq0.y, dq0.z, dq0.w,                      \
                             dq1.x, dq1.y, dq1.z, dq1.w};                     \
        _Pragma("unroll")                                                     \
        for (int u = 0; u < 8; ++u) {                                         \
            float e = src_r + dv[u];                                          \
            e = e > 0.f ? e : ALPHA * e;                                      \
            float ex = __expf(e - m_r);                                       \
            float w = (mb & (1u << u)) ? ex : 0.f;                            \
            den_reg += w;                                                     \
            AF_.e[u] = (__bf16)w;                                             \
        }                                                                     \
    }

#define K3_MFMA(AF_, B_)                                                      \
    {                                                                         \
        _Pragma("unroll")                                                     \
        for (int ft = 0; ft < 8; ++ft)                                        \
            acc[ft] = __builtin_amdgcn_mfma_f32_32x32x16_bf16(                \
                AF_.v, B_[ft], acc[ft], 0, 0, 0);                             \
    }

    bf16x8 BE[8], BO[8];
    K3_LOADB(BE, jbeg);                     // half-step 0
    unsigned mw = grow[0];

    for (int s = 0; s < STEPS; ++s) {
        const int j16 = jbeg + s * 32;
        unsigned mwn = grow[(s + 1 < STEPS) ? s + 1 : 0];
        // ---- even half (koff 0): consume BE, prefetch BO for koff 16 ----
        K3_LOADB(BO, j16 + 16);
        union { bf16x8 v; __bf16 e[8]; } afe;
        K3_WCOMP(s, mw, 0, afe);
        K3_MFMA(afe, BE);
        // ---- odd half (koff 16): consume BO, prefetch BE for step s+1 ----
        {
            const int jn = (s + 1 < STEPS) ? j16 + 32 : jbeg;
            K3_LOADB(BE, jn);
        }
        union { bf16x8 v; __bf16 e[8]; } afo;
        K3_WCOMP(s, mw, 16, afo);
        K3_MFMA(afo, BO);
        mw = mwn;
    }
    // epilogue: den = lane l + lane l+32 hold the two k-halves of row q
    den_reg += __shfl_xor(den_reg, 32);
    if (hi == 0) den[(size_t)seg * NN + row] = den_reg;
    // num: C layout col = l&31, row m = (rg&3)+8*(rg>>2)+4*hi
    #pragma unroll
    for (int ft = 0; ft < 8; ++ft)
        #pragma unroll
        for (int rg = 0; rg < 16; ++rg) {
            int m = (rg & 3) + 8 * (rg >> 2) + 4 * hi;
            num[((size_t)seg * NN + i0 + wv * 32 + m) * FF + ft * 32 + q] = acc[ft][rg];
        }
}

// ---------------- K4: out = relu( sum_s num / sum_s den ) -----------------
__global__ __launch_bounds__(256) void k4_out(const float* __restrict__ num,
                                              const float* __restrict__ den,
                                              float* __restrict__ out) {
    size_t f4 = (size_t)blockIdx.x * 256 + threadIdx.x;
    int i = (int)(f4 >> 6);
    int c4 = (int)(f4 & 63) << 2;
    float4 s = make_float4(0.f, 0.f, 0.f, 0.f);
    float d = 0.f;
    #pragma unroll
    for (int sg = 0; sg < SS; ++sg) {
        float4 v = *(const float4*)&num[((size_t)sg * NN + i) * FF + c4];
        s.x += v.x; s.y += v.y; s.z += v.z; s.w += v.w;
        d += den[(size_t)sg * NN + i];
    }
    float inv = 1.f / d;
    float4 o;
    o.x = fmaxf(s.x * inv, 0.f);
    o.y = fmaxf(s.y * inv, 0.f);
    o.z = fmaxf(s.z * inv, 0.f);
    o.w = fmaxf(s.w * inv, 0.f);
    *(float4*)&out[(size_t)i * FF + c4] = o;
}

extern "C" void kernel_launch(void* const* d_in, const int* in_sizes, int n_in,
                              void* d_out, int out_size, void* d_ws, size_t ws_size,
                              hipStream_t stream) {
    const float* X  = (const float*)d_in[0];
    const int*  adj = (const int*)d_in[1];
    const float* W  = (const float*)d_in[2];
    const float* a  = (const float*)d_in[3];
    float* out = (float*)d_out;
    char* ws = (char*)d_ws;

    const size_t off_hT   = 0;                                  // hi only: 4 MB
    const size_t off_wt   = off_hT + (size_t)FF * NN * 2;
    const size_t off_src  = off_wt + (size_t)2 * FF * FF * 2;
    const size_t off_dst  = off_src + (size_t)NN * 4;
    const size_t off_maxd = off_dst + (size_t)NN * 4;
    const size_t off_num  = off_maxd + 256;
    const size_t off_den  = off_num + (size_t)SS * NN * FF * 4;
    const size_t off_bits = off_den + (size_t)SS * NN * 4;

    __bf16* hT_ws = (__bf16*)(ws + off_hT);
    __bf16* wt_ws = (__bf16*)(ws + off_wt);
    float* src_ws = (float*)(ws + off_src);
    float* dst_ws = (float*)(ws + off_dst);
    float* maxd   = (float*)(ws + off_maxd);
    float* num_ws = (float*)(ws + off_num);
    float* den_ws = (float*)(ws + off_den);
    unsigned* bits_ws = (unsigned*)(ws + off_bits);

    k2a_pack<<<2048, 256, 0, stream>>>(adj, bits_ws);
    k0_wt<<<dim3(FF / 64, FF / 64), 256, 0, stream>>>(W, wt_ws);
    k1_h<<<NN / 32, 256, 0, stream>>>(X, wt_ws, a, hT_ws, src_ws, dst_ws);
    k2b_max<<<1, 256, 0, stream>>>(dst_ws, maxd);
    k3_attn<<<(NN / BI) * SS, 256, 0, stream>>>(bits_ws, hT_ws, src_ws, dst_ws, maxd,
                                                num_ws, den_ws);
    k4_out<<<(NN * FF / 4) / 256, 256, 0, stream>>>(num_ws, den_ws, out);
}

// Round 10
// 447.334 us; speedup vs baseline: 1.1745x; 1.1745x over previous
//
#include <hip/hip_runtime.h>
#include <math.h>

#define NN 8192
#define FF 256
#define ALPHA 0.2f
#define SS 8                 // j-segments
#define JSEG (NN / SS)       // 1024
#define STEPS (JSEG / 32)    // 32 steps of 32 j each (even)
#define BI 128               // i-rows per k3 block (8 waves x 16 rows)

typedef __bf16 bf16x8 __attribute__((ext_vector_type(8)));
typedef __bf16 bf16x4 __attribute__((ext_vector_type(4)));
typedef float  f32x4  __attribute__((ext_vector_type(4)));

__device__ __forceinline__ void dma16(const void* g, void* l) {
    __builtin_amdgcn_global_load_lds((const __attribute__((address_space(1))) void*)g,
                                     (__attribute__((address_space(3))) void*)l,
                                     16, 0, 0);
}

#define VMCNT0   asm volatile("s_waitcnt vmcnt(0)" ::: "memory")
#define LGKM0    asm volatile("s_waitcnt lgkmcnt(0)" ::: "memory")
#define BARRIER  asm volatile("s_barrier" ::: "memory")
#define FENCE    asm volatile("" ::: "memory")

// ---------------- K0: WT[hl][n][k] bf16 hi/lo from W[k][n] fp32 -----------
__global__ __launch_bounds__(256) void k0_wt(const float* __restrict__ W,
                                             __bf16* __restrict__ WT) {
    __shared__ float ts[64][65];
    const int t = threadIdx.x;
    const int k0 = blockIdx.x * 64;
    const int n0 = blockIdx.y * 64;
    #pragma unroll
    for (int r = 0; r < 4; ++r) {
        int krow = r * 16 + (t >> 4);
        int nc4 = (t & 15) * 4;
        *(float4*)&ts[krow][nc4] = *(const float4*)&W[(size_t)(k0 + krow) * FF + n0 + nc4];
    }
    __syncthreads();
    const int nloc = t >> 2;
    const int kc = (t & 3) * 16;
    union { bf16x8 v[2]; __bf16 e[16]; } hi, lo;
    #pragma unroll
    for (int u = 0; u < 16; ++u) {
        float x = ts[kc + u][nloc];
        __bf16 h1 = (__bf16)x;
        hi.e[u] = h1;
        lo.e[u] = (__bf16)(x - (float)h1);
    }
    size_t base = (size_t)(n0 + nloc) * FF + k0 + kc;
    *(bf16x8*)&WT[base] = hi.v[0];
    *(bf16x8*)&WT[base + 8] = hi.v[1];
    size_t lbase = (size_t)FF * FF + base;
    *(bf16x8*)&WT[lbase] = lo.v[0];
    *(bf16x8*)&WT[lbase + 8] = lo.v[1];
}

// ---------------- K1: MFMA h-tile -> hT(hi, transposed) + src/dst ---------
__global__ __launch_bounds__(256) void k1_h(const float* __restrict__ X,
                                            const __bf16* __restrict__ WT,
                                            const float* __restrict__ a,
                                            __bf16* __restrict__ hT,
                                            float* __restrict__ src,
                                            float* __restrict__ dst) {
    __shared__ __bf16 ax[2][32][40];
    __shared__ float hs[32][264];
    __shared__ float red[2][4][32];
    const int t = threadIdx.x;
    const int i0 = blockIdx.x * 32;
    const int l = t & 63, wv = t >> 6, ln = l & 15, g = l >> 4;
    f32x4 acc[2][4];
    #pragma unroll
    for (int mt = 0; mt < 2; ++mt)
        #pragma unroll
        for (int nt = 0; nt < 4; ++nt)
            acc[mt][nt] = (f32x4){0.f, 0.f, 0.f, 0.f};

    for (int ks = 0; ks < 8; ++ks) {
        const int k0 = ks * 32;
        {
            int row = t >> 3, c4 = (t & 7) * 4;
            float4 xv = *(const float4*)&X[(size_t)(i0 + row) * FF + k0 + c4];
            bf16x4 hi4, lo4;
            float xs_[4] = {xv.x, xv.y, xv.z, xv.w};
            #pragma unroll
            for (int u = 0; u < 4; ++u) {
                __bf16 h1 = (__bf16)xs_[u];
                hi4[u] = h1;
                lo4[u] = (__bf16)(xs_[u] - (float)h1);
            }
            *(bf16x4*)&ax[0][row][c4] = hi4;
            *(bf16x4*)&ax[1][row][c4] = lo4;
        }
        __syncthreads();
        bf16x8 ah[2], al[2];
        ah[0] = *(bf16x8*)&ax[0][ln][g * 8];
        ah[1] = *(bf16x8*)&ax[0][16 + ln][g * 8];
        al[0] = *(bf16x8*)&ax[1][ln][g * 8];
        al[1] = *(bf16x8*)&ax[1][16 + ln][g * 8];
        #pragma unroll
        for (int nt = 0; nt < 4; ++nt) {
            const int n = wv * 64 + nt * 16 + ln;
            bf16x8 bh8 = *(const bf16x8*)&WT[(size_t)n * FF + k0 + g * 8];
            bf16x8 bl8 = *(const bf16x8*)&WT[(size_t)(FF + n) * FF + k0 + g * 8];
            #pragma unroll
            for (int mt = 0; mt < 2; ++mt) {
                acc[mt][nt] = __builtin_amdgcn_mfma_f32_16x16x32_bf16(ah[mt], bh8, acc[mt][nt], 0, 0, 0);
                acc[mt][nt] = __builtin_amdgcn_mfma_f32_16x16x32_bf16(ah[mt], bl8, acc[mt][nt], 0, 0, 0);
                acc[mt][nt] = __builtin_amdgcn_mfma_f32_16x16x32_bf16(al[mt], bh8, acc[mt][nt], 0, 0, 0);
            }
        }
        __syncthreads();
    }
    float an[4], ad[4];
    #pragma unroll
    for (int nt = 0; nt < 4; ++nt) {
        an[nt] = a[wv * 64 + nt * 16 + ln];
        ad[nt] = a[FF + wv * 64 + nt * 16 + ln];
    }
    float sp[2][4], dp[2][4];
    #pragma unroll
    for (int mt = 0; mt < 2; ++mt)
        #pragma unroll
        for (int rg = 0; rg < 4; ++rg) { sp[mt][rg] = 0.f; dp[mt][rg] = 0.f; }
    #pragma unroll
    for (int mt = 0; mt < 2; ++mt)
        #pragma unroll
        for (int nt = 0; nt < 4; ++nt)
            #pragma unroll
            for (int rg = 0; rg < 4; ++rg) {
                float v = acc[mt][nt][rg];
                hs[mt * 16 + g * 4 + rg][wv * 64 + nt * 16 + ln] = v;
                sp[mt][rg] += v * an[nt];
                dp[mt][rg] += v * ad[nt];
            }
    #pragma unroll
    for (int mk = 1; mk < 16; mk <<= 1)
        #pragma unroll
        for (int mt = 0; mt < 2; ++mt)
            #pragma unroll
            for (int rg = 0; rg < 4; ++rg) {
                sp[mt][rg] += __shfl_xor(sp[mt][rg], mk);
                dp[mt][rg] += __shfl_xor(dp[mt][rg], mk);
            }
    if (ln == 0) {
        #pragma unroll
        for (int mt = 0; mt < 2; ++mt)
            #pragma unroll
            for (int rg = 0; rg < 4; ++rg) {
                red[0][wv][mt * 16 + g * 4 + rg] = sp[mt][rg];
                red[1][wv][mt * 16 + g * 4 + rg] = dp[mt][rg];
            }
    }
    __syncthreads();
    if (t < 32) {
        src[i0 + t] = red[0][0][t] + red[0][1][t] + red[0][2][t] + red[0][3][t];
        dst[i0 + t] = red[1][0][t] + red[1][1][t] + red[1][2][t] + red[1][3][t];
    }
    {
        const int f = t;
        #pragma unroll
        for (int jc = 0; jc < 4; ++jc) {
            union { bf16x8 v; __bf16 e[8]; } hi;
            #pragma unroll
            for (int u = 0; u < 8; ++u) {
                float x = hs[jc * 8 + u][f];
                hi.e[u] = (__bf16)x;
            }
            *(bf16x8*)&hT[(size_t)f * NN + i0 + jc * 8] = hi.v;
        }
    }
}

// ---------------- K2a: pack adj int32 -> 1 bit/elem (natural j order) -----
__global__ __launch_bounds__(256) void k2a_pack(const int* __restrict__ adj,
                                                unsigned* __restrict__ bits) {
    const size_t total4 = (size_t)NN * NN / 4;
    const int l = threadIdx.x & 63;
    const int base = l & 56;
    size_t t = (size_t)blockIdx.x * 256 + threadIdx.x;
    const size_t stride = (size_t)gridDim.x * 256;
    for (; t < total4; t += stride) {
        int4 v = ((const int4*)adj)[t];
        unsigned nib = (unsigned)(v.x > 0) | ((unsigned)(v.y > 0) << 1)
                     | ((unsigned)(v.z > 0) << 2) | ((unsigned)(v.w > 0) << 3);
        unsigned w = 0;
        #pragma unroll
        for (int k = 0; k < 8; ++k)
            w |= (unsigned)__shfl((int)nib, base + k) << (4 * k);
        if ((l & 7) == 0)
            bits[t >> 3] = w;
    }
}

// ---------------- K2b: maxd = max_j dst_j ---------------------------------
__global__ __launch_bounds__(256) void k2b_max(const float* __restrict__ dst,
                                               float* __restrict__ maxd) {
    __shared__ float red[256];
    float m = -1e30f;
    #pragma unroll
    for (int r = 0; r < NN / 1024; ++r) {
        float4 v = *(const float4*)&dst[(r * 256 + threadIdx.x) * 4];
        m = fmaxf(m, fmaxf(fmaxf(v.x, v.y), fmaxf(v.z, v.w)));
    }
    red[threadIdx.x] = m;
    __syncthreads();
    for (int s = 128; s > 0; s >>= 1) {
        if (threadIdx.x < s) red[threadIdx.x] = fmaxf(red[threadIdx.x], red[threadIdx.x + s]);
        __syncthreads();
    }
    if (threadIdx.x == 0) maxd[0] = red[0];
}

// ---------------- K3: R6 structure + seg->XCD affinity swizzle ------------
// Identical to the best-measured config (R6, 446us) except ONE change:
// seg = bid&7 (was bid>>6). With round-robin block->XCD dispatch, each
// XCD now hosts only blocks of one seg -> its L2 B-working-set is that
// seg's 512 KB hT slice (12% of L2) instead of the full 4 MB (100% of
// L2, thrashing with mask/dst/fill residue). T1 in its proper regime:
// co-resident neighbor blocks share one operand panel.
__global__ __launch_bounds__(512, 4) void k3_attn(const unsigned* __restrict__ bits,
                                                  const __bf16* __restrict__ hT,
                                                  const float* __restrict__ src,
                                                  const float* __restrict__ dst,
                                                  const float* __restrict__ maxd,
                                                  float* __restrict__ num,
                                                  float* __restrict__ den) {
    __shared__ __bf16 bh[2][1024 * 8];      // 32 KB B-tile double buffer
    __shared__ float dsts[JSEG];            // 4 KB dst segment
    const int t = threadIdx.x;
    const int l = t & 63, wv = t >> 6, ln = l & 15, g = l >> 4;
    const int seg = blockIdx.x & 7;         // seg -> XCD affinity
    const int it = blockIdx.x >> 3;         // NN/BI = 64 i-tiles
    const int i0 = it * BI;
    const int jbeg = seg * JSEG;
    const int row = i0 + wv * 16 + ln;
    const float maxdv = maxd[0];
    const float src_r = src[row];
    const float e0 = src_r + maxdv;
    const float m_r = e0 > 0.f ? e0 : ALPHA * e0;   // per-row shift >= row max

    // DMA descriptors: 2 chunks/thread (1024 chunks total), lane-linear LDS,
    // swizzle on gaddr. Chunk c = f*4+pc holds hT[f][j0+(pc^((f>>1)&3))*8..+8]
    // at byte c*16.
    int ga[2], cb[2];
    #pragma unroll
    for (int r = 0; r < 2; ++r) {
        int cbase = r * 512 + wv * 64;
        int c = cbase + l;
        int f = c >> 2;
        int pc = c & 3;
        int jc = pc ^ ((f >> 1) & 3);
        ga[r] = f * NN + jc * 8;        // hi-only hT
        cb[r] = __builtin_amdgcn_readfirstlane(cbase);
    }
    // B-read base (BYTES): f=nt*16+ln -> elem off = f*32 + (g^sw)*8
    const int rb = ln * 64 + ((g ^ ((ln >> 1) & 3)) * 16);
    const char* bh0 = (const char*)&bh[0][0] + rb;
    const char* bh1 = (const char*)&bh[1][0] + rb;

    // mask source: word s of this row's segment
    const unsigned* grow = bits + (size_t)row * (NN / 32) + (jbeg >> 5);

    // prologue: DMA tile 0 -> bh[0]; dst segment -> LDS; mask pair 0 -> regs
    #pragma unroll
    for (int r = 0; r < 2; ++r)
        dma16(&hT[ga[r] + jbeg], &bh[0][cb[r] * 8]);
    FENCE;
    if (t < 256) *(float4*)&dsts[t * 4] = *(const float4*)&dst[jbeg + t * 4];
    uint2 wp = *(const uint2*)&grow[0];
    uint2 wpn = wp;
    __syncthreads();            // drains vmcnt(0)+lgkmcnt(0): tile 0 + dsts ready

    float den_reg = 0.f;
    f32x4 acc[16];
    #pragma unroll
    for (int nt = 0; nt < 16; ++nt) acc[nt] = (f32x4){0.f, 0.f, 0.f, 0.f};

#define K3_WCOMP(S_, MW_, AF_)                                                \
    {                                                                         \
        unsigned mb = ((MW_) >> (g * 8)) & 0xffu;                             \
        const float* dp_ = &dsts[(S_) * 32 + g * 8];                          \
        float4 dq0 = *(const float4*)dp_;                                     \
        float4 dq1 = *(const float4*)(dp_ + 4);                               \
        const float dv[8] = {dq0.x, dq0.y, dq0.z, dq0.w,                      \
                             dq1.x, dq1.y, dq1.z, dq1.w};                     \
        _Pragma("unroll")                                                     \
        for (int u = 0; u < 8; ++u) {                                         \
            float e = src_r + dv[u];                                          \
            e = e > 0.f ? e : ALPHA * e;                                      \
            float ex = __expf(e - m_r);                                       \
            float w = (mb & (1u << u)) ? ex : 0.f;                            \
            den_reg += w;                                                     \
            AF_.e[u] = (__bf16)w;                                             \
        }                                                                     \
    }

#define K3_MFMA(AF_, BP_)                                                     \
    {                                                                         \
        _Pragma("unroll")                                                     \
        for (int nt = 0; nt < 16; ++nt) {                                     \
            bf16x8 bfr = *(const bf16x8*)((BP_) + nt * 1024);                 \
            acc[nt] = __builtin_amdgcn_mfma_f32_16x16x32_bf16(                \
                AF_.v, bfr, acc[nt], 0, 0, 0);                                \
        }                                                                     \
    }

    for (int s = 0; s < STEPS; s += 2) {
        // ---- even: tile s in bh[0] ----
        union { bf16x8 v; __bf16 e[8]; } afe;
        K3_WCOMP(s, wp.x, afe);
        FENCE; VMCNT0; LGKM0; BARRIER;
        #pragma unroll
        for (int r = 0; r < 2; ++r)
            dma16(&hT[ga[r] + jbeg + (s + 1) * 32], &bh[1][cb[r] * 8]);
        if (s + 2 < STEPS) wpn = *(const uint2*)&grow[s + 2];
        FENCE;
        K3_MFMA(afe, bh0);
        // ---- odd: tile s+1 in bh[1] ----
        union { bf16x8 v; __bf16 e[8]; } afo;
        K3_WCOMP(s + 1, wp.y, afo);
        FENCE; VMCNT0; LGKM0; BARRIER;
        {
            int sn = (s + 2 < STEPS) ? s + 2 : 0;
            #pragma unroll
            for (int r = 0; r < 2; ++r)
                dma16(&hT[ga[r] + jbeg + sn * 32], &bh[0][cb[r] * 8]);
        }
        FENCE;
        K3_MFMA(afo, bh1);
        wp = wpn;
    }
    // epilogue: den = reduce over g lanes (xor bits 4,5)
    den_reg += __shfl_xor(den_reg, 16);
    den_reg += __shfl_xor(den_reg, 32);
    if (g == 0) den[(size_t)seg * NN + row] = den_reg;
    // num: C layout col=ln, row m=g*4+rg within wave's 16-row tile
    #pragma unroll
    for (int nt = 0; nt < 16; ++nt)
        #pragma unroll
        for (int rg = 0; rg < 4; ++rg)
            num[((size_t)seg * NN + i0 + wv * 16 + g * 4 + rg) * FF
                + nt * 16 + ln] = acc[nt][rg];
}

// ---------------- K4: out = relu( sum_s num / sum_s den ) -----------------
__global__ __launch_bounds__(256) void k4_out(const float* __restrict__ num,
                                              const float* __restrict__ den,
                                              float* __restrict__ out) {
    size_t f4 = (size_t)blockIdx.x * 256 + threadIdx.x;
    int i = (int)(f4 >> 6);
    int c4 = (int)(f4 & 63) << 2;
    float4 s = make_float4(0.f, 0.f, 0.f, 0.f);
    float d = 0.f;
    #pragma unroll
    for (int sg = 0; sg < SS; ++sg) {
        float4 v = *(const float4*)&num[((size_t)sg * NN + i) * FF + c4];
        s.x += v.x; s.y += v.y; s.z += v.z; s.w += v.w;
        d += den[(size_t)sg * NN + i];
    }
    float inv = 1.f / d;
    float4 o;
    o.x = fmaxf(s.x * inv, 0.f);
    o.y = fmaxf(s.y * inv, 0.f);
    o.z = fmaxf(s.z * inv, 0.f);
    o.w = fmaxf(s.w * inv, 0.f);
    *(float4*)&out[(size_t)i * FF + c4] = o;
}

extern "C" void kernel_launch(void* const* d_in, const int* in_sizes, int n_in,
                              void* d_out, int out_size, void* d_ws, size_t ws_size,
                              hipStream_t stream) {
    const float* X  = (const float*)d_in[0];
    const int*  adj = (const int*)d_in[1];
    const float* W  = (const float*)d_in[2];
    const float* a  = (const float*)d_in[3];
    float* out = (float*)d_out;
    char* ws = (char*)d_ws;

    const size_t off_hT   = 0;                                  // hi only: 4 MB
    const size_t off_wt   = off_hT + (size_t)FF * NN * 2;
    const size_t off_src  = off_wt + (size_t)2 * FF * FF * 2;
    const size_t off_dst  = off_src + (size_t)NN * 4;
    const size_t off_maxd = off_dst + (size_t)NN * 4;
    const size_t off_num  = off_maxd + 256;
    const size_t off_den  = off_num + (size_t)SS * NN * FF * 4;
    const size_t off_bits = off_den + (size_t)SS * NN * 4;

    __bf16* hT_ws = (__bf16*)(ws + off_hT);
    __bf16* wt_ws = (__bf16*)(ws + off_wt);
    float* src_ws = (float*)(ws + off_src);
    float* dst_ws = (float*)(ws + off_dst);
    float* maxd   = (float*)(ws + off_maxd);
    float* num_ws = (float*)(ws + off_num);
    float* den_ws = (float*)(ws + off_den);
    unsigned* bits_ws = (unsigned*)(ws + off_bits);

    k2a_pack<<<2048, 256, 0, stream>>>(adj, bits_ws);
    k0_wt<<<dim3(FF / 64, FF / 64), 256, 0, stream>>>(W, wt_ws);
    k1_h<<<NN / 32, 256, 0, stream>>>(X, wt_ws, a, hT_ws, src_ws, dst_ws);
    k2b_max<<<1, 256, 0, stream>>>(dst_ws, maxd);
    k3_attn<<<(NN / BI) * SS, 512, 0, stream>>>(bits_ws, hT_ws, src_ws, dst_ws, maxd,
                                                num_ws, den_ws);
    k4_out<<<(NN * FF / 4) / 256, 256, 0, stream>>>(num_ws, den_ws, out);
}

// Round 11
// 446.419 us; speedup vs baseline: 1.1769x; 1.0020x over previous
//
#include <hip/hip_runtime.h>
#include <math.h>

#define NN 8192
#define FF 256
#define ALPHA 0.2f
#define SS 8                 // j-segments
#define JSEG (NN / SS)       // 1024
#define STEPS (JSEG / 32)    // 32 steps of 32 j each (even)
#define BI 128               // i-rows per k3 block (8 waves x 16 rows)

typedef __bf16 bf16x8 __attribute__((ext_vector_type(8)));
typedef __bf16 bf16x4 __attribute__((ext_vector_type(4)));
typedef float  f32x4  __attribute__((ext_vector_type(4)));

__device__ __forceinline__ void dma16(const void* g, void* l) {
    __builtin_amdgcn_global_load_lds((const __attribute__((address_space(1))) void*)g,
                                     (__attribute__((address_space(3))) void*)l,
                                     16, 0, 0);
}

#define VMCNT0   asm volatile("s_waitcnt vmcnt(0)" ::: "memory")
#define LGKM0    asm volatile("s_waitcnt lgkmcnt(0)" ::: "memory")
#define BARRIER  asm volatile("s_barrier" ::: "memory")
#define FENCE    asm volatile("" ::: "memory")

// ---------------- K0: WT[hl][n][k] bf16 hi/lo from W[k][n] fp32 -----------
__global__ __launch_bounds__(256) void k0_wt(const float* __restrict__ W,
                                             __bf16* __restrict__ WT) {
    __shared__ float ts[64][65];
    const int t = threadIdx.x;
    const int k0 = blockIdx.x * 64;
    const int n0 = blockIdx.y * 64;
    #pragma unroll
    for (int r = 0; r < 4; ++r) {
        int krow = r * 16 + (t >> 4);
        int nc4 = (t & 15) * 4;
        *(float4*)&ts[krow][nc4] = *(const float4*)&W[(size_t)(k0 + krow) * FF + n0 + nc4];
    }
    __syncthreads();
    const int nloc = t >> 2;
    const int kc = (t & 3) * 16;
    union { bf16x8 v[2]; __bf16 e[16]; } hi, lo;
    #pragma unroll
    for (int u = 0; u < 16; ++u) {
        float x = ts[kc + u][nloc];
        __bf16 h1 = (__bf16)x;
        hi.e[u] = h1;
        lo.e[u] = (__bf16)(x - (float)h1);
    }
    size_t base = (size_t)(n0 + nloc) * FF + k0 + kc;
    *(bf16x8*)&WT[base] = hi.v[0];
    *(bf16x8*)&WT[base + 8] = hi.v[1];
    size_t lbase = (size_t)FF * FF + base;
    *(bf16x8*)&WT[lbase] = lo.v[0];
    *(bf16x8*)&WT[lbase + 8] = lo.v[1];
}

// ---------------- K1: MFMA h-tile -> hT(seg-major) + src/dst + maxd -------
// hT layout CHANGE (R10 post-mortem): [seg][f][j_local] so each segment's
// B-panel is 512 KB CONTIGUOUS -> uniform 2-way L2 set pressure instead of
// 512 sets at 16/16 ways (old [f][j] 16KB-stride layout thrashed by
// associativity conflicts -> every k3 tile DMA was a conflict-miss storm).
// Also folds k2b: exact monotone-uint atomicMax of dst into maxd.
__global__ __launch_bounds__(256) void k1_h(const float* __restrict__ X,
                                            const __bf16* __restrict__ WT,
                                            const float* __restrict__ a,
                                            __bf16* __restrict__ hT,
                                            float* __restrict__ src,
                                            float* __restrict__ dst,
                                            unsigned* __restrict__ maxd) {
    __shared__ __bf16 ax[2][32][40];
    __shared__ float hs[32][264];
    __shared__ float red[2][4][32];
    const int t = threadIdx.x;
    const int i0 = blockIdx.x * 32;
    const int l = t & 63, wv = t >> 6, ln = l & 15, g = l >> 4;
    f32x4 acc[2][4];
    #pragma unroll
    for (int mt = 0; mt < 2; ++mt)
        #pragma unroll
        for (int nt = 0; nt < 4; ++nt)
            acc[mt][nt] = (f32x4){0.f, 0.f, 0.f, 0.f};

    for (int ks = 0; ks < 8; ++ks) {
        const int k0 = ks * 32;
        {
            int row = t >> 3, c4 = (t & 7) * 4;
            float4 xv = *(const float4*)&X[(size_t)(i0 + row) * FF + k0 + c4];
            bf16x4 hi4, lo4;
            float xs_[4] = {xv.x, xv.y, xv.z, xv.w};
            #pragma unroll
            for (int u = 0; u < 4; ++u) {
                __bf16 h1 = (__bf16)xs_[u];
                hi4[u] = h1;
                lo4[u] = (__bf16)(xs_[u] - (float)h1);
            }
            *(bf16x4*)&ax[0][row][c4] = hi4;
            *(bf16x4*)&ax[1][row][c4] = lo4;
        }
        __syncthreads();
        bf16x8 ah[2], al[2];
        ah[0] = *(bf16x8*)&ax[0][ln][g * 8];
        ah[1] = *(bf16x8*)&ax[0][16 + ln][g * 8];
        al[0] = *(bf16x8*)&ax[1][ln][g * 8];
        al[1] = *(bf16x8*)&ax[1][16 + ln][g * 8];
        #pragma unroll
        for (int nt = 0; nt < 4; ++nt) {
            const int n = wv * 64 + nt * 16 + ln;
            bf16x8 bh8 = *(const bf16x8*)&WT[(size_t)n * FF + k0 + g * 8];
            bf16x8 bl8 = *(const bf16x8*)&WT[(size_t)(FF + n) * FF + k0 + g * 8];
            #pragma unroll
            for (int mt = 0; mt < 2; ++mt) {
                acc[mt][nt] = __builtin_amdgcn_mfma_f32_16x16x32_bf16(ah[mt], bh8, acc[mt][nt], 0, 0, 0);
                acc[mt][nt] = __builtin_amdgcn_mfma_f32_16x16x32_bf16(ah[mt], bl8, acc[mt][nt], 0, 0, 0);
                acc[mt][nt] = __builtin_amdgcn_mfma_f32_16x16x32_bf16(al[mt], bh8, acc[mt][nt], 0, 0, 0);
            }
        }
        __syncthreads();
    }
    float an[4], ad[4];
    #pragma unroll
    for (int nt = 0; nt < 4; ++nt) {
        an[nt] = a[wv * 64 + nt * 16 + ln];
        ad[nt] = a[FF + wv * 64 + nt * 16 + ln];
    }
    float sp[2][4], dp[2][4];
    #pragma unroll
    for (int mt = 0; mt < 2; ++mt)
        #pragma unroll
        for (int rg = 0; rg < 4; ++rg) { sp[mt][rg] = 0.f; dp[mt][rg] = 0.f; }
    #pragma unroll
    for (int mt = 0; mt < 2; ++mt)
        #pragma unroll
        for (int nt = 0; nt < 4; ++nt)
            #pragma unroll
            for (int rg = 0; rg < 4; ++rg) {
                float v = acc[mt][nt][rg];
                hs[mt * 16 + g * 4 + rg][wv * 64 + nt * 16 + ln] = v;
                sp[mt][rg] += v * an[nt];
                dp[mt][rg] += v * ad[nt];
            }
    #pragma unroll
    for (int mk = 1; mk < 16; mk <<= 1)
        #pragma unroll
        for (int mt = 0; mt < 2; ++mt)
            #pragma unroll
            for (int rg = 0; rg < 4; ++rg) {
                sp[mt][rg] += __shfl_xor(sp[mt][rg], mk);
                dp[mt][rg] += __shfl_xor(dp[mt][rg], mk);
            }
    if (ln == 0) {
        #pragma unroll
        for (int mt = 0; mt < 2; ++mt)
            #pragma unroll
            for (int rg = 0; rg < 4; ++rg) {
                red[0][wv][mt * 16 + g * 4 + rg] = sp[mt][rg];
                red[1][wv][mt * 16 + g * 4 + rg] = dp[mt][rg];
            }
    }
    __syncthreads();
    if (t < 32) {
        src[i0 + t] = red[0][0][t] + red[0][1][t] + red[0][2][t] + red[0][3][t];
        float dv_ = red[1][0][t] + red[1][1][t] + red[1][2][t] + red[1][3][t];
        dst[i0 + t] = dv_;
        // exact monotone-uint max (replaces k2b); init done by k2a
        unsigned u = __float_as_uint(dv_);
        unsigned key = (u & 0x80000000u) ? ~u : (u | 0x80000000u);
        atomicMax(maxd, key);
    }
    {
        const int f = t;
        const int seg_i = i0 >> 10;             // i0 / JSEG
        const int ilb = i0 & (JSEG - 1);
        #pragma unroll
        for (int jc = 0; jc < 4; ++jc) {
            union { bf16x8 v; __bf16 e[8]; } hi;
            #pragma unroll
            for (int u = 0; u < 8; ++u) {
                float x = hs[jc * 8 + u][f];
                hi.e[u] = (__bf16)x;
            }
            *(bf16x8*)&hT[((size_t)seg_i * FF + f) * JSEG + ilb + jc * 8] = hi.v;
        }
    }
}

// ---------------- K2a: pack adj int32 -> 1 bit/elem; init maxd ------------
__global__ __launch_bounds__(256) void k2a_pack(const int* __restrict__ adj,
                                                unsigned* __restrict__ bits,
                                                unsigned* __restrict__ maxd) {
    if (blockIdx.x == 0 && threadIdx.x == 0) maxd[0] = 0u;  // key of -inf
    const size_t total4 = (size_t)NN * NN / 4;
    const int l = threadIdx.x & 63;
    const int base = l & 56;
    size_t t = (size_t)blockIdx.x * 256 + threadIdx.x;
    const size_t stride = (size_t)gridDim.x * 256;
    for (; t < total4; t += stride) {
        int4 v = ((const int4*)adj)[t];
        unsigned nib = (unsigned)(v.x > 0) | ((unsigned)(v.y > 0) << 1)
                     | ((unsigned)(v.z > 0) << 2) | ((unsigned)(v.w > 0) << 3);
        unsigned w = 0;
        #pragma unroll
        for (int k = 0; k < 8; ++k)
            w |= (unsigned)__shfl((int)nib, base + k) << (4 * k);
        if ((l & 7) == 0)
            bits[t >> 3] = w;
    }
}

// ---------------- K3: R6 structure + seg-major hT (L2 conflict fix) -------
// Identical to the 446us-verified loop except hT addressing: the block's
// B-panel is now the contiguous 512 KB slab hT[seg][.][.] -> uniform L2 set
// usage (2/16 ways) instead of 512 sets at full associativity. maxd is the
// monotone-uint key from k1 (decoded here; bit-identical max).
__global__ __launch_bounds__(512, 4) void k3_attn(const unsigned* __restrict__ bits,
                                                  const __bf16* __restrict__ hT,
                                                  const float* __restrict__ src,
                                                  const float* __restrict__ dst,
                                                  const unsigned* __restrict__ maxd,
                                                  float* __restrict__ num,
                                                  float* __restrict__ den) {
    __shared__ __bf16 bh[2][1024 * 8];      // 32 KB B-tile double buffer
    __shared__ float dsts[JSEG];            // 4 KB dst segment
    const int t = threadIdx.x;
    const int l = t & 63, wv = t >> 6, ln = l & 15, g = l >> 4;
    const int seg = blockIdx.x & 7;         // seg -> XCD affinity
    const int it = blockIdx.x >> 3;         // NN/BI = 64 i-tiles
    const int i0 = it * BI;
    const int jbeg = seg * JSEG;
    const int row = i0 + wv * 16 + ln;
    const unsigned mk_ = maxd[0];
    const float maxdv = (mk_ & 0x80000000u) ? __uint_as_float(mk_ & 0x7fffffffu)
                                            : __uint_as_float(~mk_);
    const float src_r = src[row];
    const float e0 = src_r + maxdv;
    const float m_r = e0 > 0.f ? e0 : ALPHA * e0;   // per-row shift >= row max

    // segment-local B panel (contiguous 512 KB)
    const __bf16* hTs = hT + (size_t)seg * FF * JSEG;

    // DMA descriptors: 2 chunks/thread (1024 chunks total), lane-linear LDS,
    // swizzle on gaddr. Chunk c = f*4+pc holds hTs[f][jl+(pc^((f>>1)&3))*8..+8]
    // at byte c*16.
    int ga[2], cb[2];
    #pragma unroll
    for (int r = 0; r < 2; ++r) {
        int cbase = r * 512 + wv * 64;
        int c = cbase + l;
        int f = c >> 2;
        int pc = c & 3;
        int jc = pc ^ ((f >> 1) & 3);
        ga[r] = f * JSEG + jc * 8;      // seg-local offset
        cb[r] = __builtin_amdgcn_readfirstlane(cbase);
    }
    // B-read base (BYTES): f=nt*16+ln -> elem off = f*32 + (g^sw)*8
    const int rb = ln * 64 + ((g ^ ((ln >> 1) & 3)) * 16);
    const char* bh0 = (const char*)&bh[0][0] + rb;
    const char* bh1 = (const char*)&bh[1][0] + rb;

    // mask source: word s of this row's segment
    const unsigned* grow = bits + (size_t)row * (NN / 32) + (jbeg >> 5);

    // prologue: DMA tile 0 -> bh[0]; dst segment -> LDS; mask pair 0 -> regs
    #pragma unroll
    for (int r = 0; r < 2; ++r)
        dma16(&hTs[ga[r]], &bh[0][cb[r] * 8]);
    FENCE;
    if (t < 256) *(float4*)&dsts[t * 4] = *(const float4*)&dst[jbeg + t * 4];
    uint2 wp = *(const uint2*)&grow[0];
    uint2 wpn = wp;
    __syncthreads();            // drains vmcnt(0)+lgkmcnt(0): tile 0 + dsts ready

    float den_reg = 0.f;
    f32x4 acc[16];
    #pragma unroll
    for (int nt = 0; nt < 16; ++nt) acc[nt] = (f32x4){0.f, 0.f, 0.f, 0.f};

#define K3_WCOMP(S_, MW_, AF_)                                                \
    {                                                                         \
        unsigned mb = ((MW_) >> (g * 8)) & 0xffu;                             \
        const float* dp_ = &dsts[(S_) * 32 + g * 8];                          \
        float4 dq0 = *(const float4*)dp_;                                     \
        float4 dq1 = *(const float4*)(dp_ + 4);                               \
        const float dv[8] = {dq0.x, dq0.y, dq0.z, dq0.w,                      \
                             dq1.x, dq1.y, dq1.z, dq1.w};                     \
        _Pragma("unroll")                                                     \
        for (int u = 0; u < 8; ++u) {                                         \
            float e = src_r + dv[u];                                          \
            e = e > 0.f ? e : ALPHA * e;                                      \
            float ex = __expf(e - m_r);                                       \
            float w = (mb & (1u << u)) ? ex : 0.f;                            \
            den_reg += w;                                                     \
            AF_.e[u] = (__bf16)w;                                             \
        }                                                                     \
    }

#define K3_MFMA(AF_, BP_)                                                     \
    {                                                                         \
        _Pragma("unroll")                                                     \
        for (int nt = 0; nt < 16; ++nt) {                                     \
            bf16x8 bfr = *(const bf16x8*)((BP_) + nt * 1024);                 \
            acc[nt] = __builtin_amdgcn_mfma_f32_16x16x32_bf16(                \
                AF_.v, bfr, acc[nt], 0, 0, 0);                                \
        }                                                                     \
    }

    for (int s = 0; s < STEPS; s += 2) {
        // ---- even: tile s in bh[0] ----
        union { bf16x8 v; __bf16 e[8]; } afe;
        K3_WCOMP(s, wp.x, afe);
        FENCE; VMCNT0; LGKM0; BARRIER;
        #pragma unroll
        for (int r = 0; r < 2; ++r)
            dma16(&hTs[ga[r] + (s + 1) * 32], &bh[1][cb[r] * 8]);
        if (s + 2 < STEPS) wpn = *(const uint2*)&grow[s + 2];
        FENCE;
        K3_MFMA(afe, bh0);
        // ---- odd: tile s+1 in bh[1] ----
        union { bf16x8 v; __bf16 e[8]; } afo;
        K3_WCOMP(s + 1, wp.y, afo);
        FENCE; VMCNT0; LGKM0; BARRIER;
        {
            int sn = (s + 2 < STEPS) ? s + 2 : 0;
            #pragma unroll
            for (int r = 0; r < 2; ++r)
                dma16(&hTs[ga[r] + sn * 32], &bh[0][cb[r] * 8]);
        }
        FENCE;
        K3_MFMA(afo, bh1);
        wp = wpn;
    }
    // epilogue: den = reduce over g lanes (xor bits 4,5)
    den_reg += __shfl_xor(den_reg, 16);
    den_reg += __shfl_xor(den_reg, 32);
    if (g == 0) den[(size_t)seg * NN + row] = den_reg;
    // num: C layout col=ln, row m=g*4+rg within wave's 16-row tile
    #pragma unroll
    for (int nt = 0; nt < 16; ++nt)
        #pragma unroll
        for (int rg = 0; rg < 4; ++rg)
            num[((size_t)seg * NN + i0 + wv * 16 + g * 4 + rg) * FF
                + nt * 16 + ln] = acc[nt][rg];
}

// ---------------- K4: out = relu( sum_s num / sum_s den ) -----------------
__global__ __launch_bounds__(256) void k4_out(const float* __restrict__ num,
                                              const float* __restrict__ den,
                                              float* __restrict__ out) {
    size_t f4 = (size_t)blockIdx.x * 256 + threadIdx.x;
    int i = (int)(f4 >> 6);
    int c4 = (int)(f4 & 63) << 2;
    float4 s = make_float4(0.f, 0.f, 0.f, 0.f);
    float d = 0.f;
    #pragma unroll
    for (int sg = 0; sg < SS; ++sg) {
        float4 v = *(const float4*)&num[((size_t)sg * NN + i) * FF + c4];
        s.x += v.x; s.y += v.y; s.z += v.z; s.w += v.w;
        d += den[(size_t)sg * NN + i];
    }
    float inv = 1.f / d;
    float4 o;
    o.x = fmaxf(s.x * inv, 0.f);
    o.y = fmaxf(s.y * inv, 0.f);
    o.z = fmaxf(s.z * inv, 0.f);
    o.w = fmaxf(s.w * inv, 0.f);
    *(float4*)&out[(size_t)i * FF + c4] = o;
}

extern "C" void kernel_launch(void* const* d_in, const int* in_sizes, int n_in,
                              void* d_out, int out_size, void* d_ws, size_t ws_size,
                              hipStream_t stream) {
    const float* X  = (const float*)d_in[0];
    const int*  adj = (const int*)d_in[1];
    const float* W  = (const float*)d_in[2];
    const float* a  = (const float*)d_in[3];
    float* out = (float*)d_out;
    char* ws = (char*)d_ws;

    const size_t off_hT   = 0;                                  // hi only: 4 MB
    const size_t off_wt   = off_hT + (size_t)FF * NN * 2;
    const size_t off_src  = off_wt + (size_t)2 * FF * FF * 2;
    const size_t off_dst  = off_src + (size_t)NN * 4;
    const size_t off_maxd = off_dst + (size_t)NN * 4;
    const size_t off_num  = off_maxd + 256;
    const size_t off_den  = off_num + (size_t)SS * NN * FF * 4;
    const size_t off_bits = off_den + (size_t)SS * NN * 4;

    __bf16* hT_ws = (__bf16*)(ws + off_hT);
    __bf16* wt_ws = (__bf16*)(ws + off_wt);
    float* src_ws = (float*)(ws + off_src);
    float* dst_ws = (float*)(ws + off_dst);
    unsigned* maxd = (unsigned*)(ws + off_maxd);
    float* num_ws = (float*)(ws + off_num);
    float* den_ws = (float*)(ws + off_den);
    unsigned* bits_ws = (unsigned*)(ws + off_bits);

    k2a_pack<<<2048, 256, 0, stream>>>(adj, bits_ws, maxd);
    k0_wt<<<dim3(FF / 64, FF / 64), 256, 0, stream>>>(W, wt_ws);
    k1_h<<<NN / 32, 256, 0, stream>>>(X, wt_ws, a, hT_ws, src_ws, dst_ws, maxd);
    k3_attn<<<(NN / BI) * SS, 512, 0, stream>>>(bits_ws, hT_ws, src_ws, dst_ws, maxd,
                                                num_ws, den_ws);
    k4_out<<<(NN * FF / 4) / 256, 256, 0, stream>>>(num_ws, den_ws, out);
}